// Round 1
// baseline (640.647 us; speedup 1.0000x reference)
//
#include <hip/hip_runtime.h>

typedef unsigned short u16;
using floatx4 = __attribute__((ext_vector_type(4))) float;
using short8  = __attribute__((ext_vector_type(8))) short;

__device__ __forceinline__ u16 f2bf(float f){
  unsigned int u = __float_as_uint(f);
  u += 0x7fffu + ((u >> 16) & 1u);   // round-to-nearest-even
  return (u16)(u >> 16);
}

// ---------------------------------------------------------------------------
// conv_rowsum: one WAVE per row (no LDS, no barriers):
//   - writes bf16 copy lb (201 MB) with 16 B/lane non-temporal stores
//   - dinv[row] = d!=0 ? rsqrt(sum_j |L[row][j]|) : 0
// rows 0..4095 -> L0, 4096..12287 -> L1, 12288..16383 -> L2
// ---------------------------------------------------------------------------
__global__ __launch_bounds__(256) void conv_rowsum_kernel(
    const float* __restrict__ L0, const float* __restrict__ L1,
    const float* __restrict__ L2, u16* __restrict__ lb,
    float* __restrict__ dinv)
{
  int row  = blockIdx.x * 4 + (threadIdx.x >> 6);
  int lane = threadIdx.x & 63;
  const float* L; int N; size_t doff;
  if (row < 4096)       { L = L0 + (size_t)row * 4096;  N = 4096; doff = (size_t)row * 4096; }
  else if (row < 12288) { int r = row - 4096;
                          L = L1 + (size_t)r * 8192;    N = 8192; doff = 16777216u + (size_t)r * 8192; }
  else                  { int r = row - 12288;
                          L = L2 + (size_t)r * 4096;    N = 4096; doff = 83886080u + (size_t)r * 4096; }
  u16* dst = lb + doff;
  float s = 0.f;
  for (int i = lane * 8; i < N; i += 512){
    float4 va = *(const float4*)(L + i);
    float4 vb = *(const float4*)(L + i + 4);
    s += fabsf(va.x) + fabsf(va.y) + fabsf(va.z) + fabsf(va.w)
       + fabsf(vb.x) + fabsf(vb.y) + fabsf(vb.z) + fabsf(vb.w);
    short8 o;
    o[0] = (short)f2bf(va.x); o[1] = (short)f2bf(va.y);
    o[2] = (short)f2bf(va.z); o[3] = (short)f2bf(va.w);
    o[4] = (short)f2bf(vb.x); o[5] = (short)f2bf(vb.y);
    o[6] = (short)f2bf(vb.z); o[7] = (short)f2bf(vb.w);
    __builtin_nontemporal_store(o, (short8*)(dst + i));
  }
  #pragma unroll
  for (int off = 32; off > 0; off >>= 1) s += __shfl_down(s, off);
  if (lane == 0) dinv[row] = (s != 0.f) ? rsqrtf(s) : 0.f;
}

// ---------------------------------------------------------------------------
// xw: Yst[c][j] = bf16( dinv[j] * (x @ W_layer)[j][c] )  -- TRANSPOSED output
// ---------------------------------------------------------------------------
__global__ __launch_bounds__(256) void xw_kernel(
    const float* __restrict__ x0, const float* __restrict__ x1,
    const float* __restrict__ x2, const float* __restrict__ xbuf,
    const float* __restrict__ W0c, const float* __restrict__ W1c,
    const float* __restrict__ W2c, int layer,
    const float* __restrict__ dinv,
    u16* __restrict__ yst0, u16* __restrict__ yst1, u16* __restrict__ yst2)
{
  int grow0 = blockIdx.x * 64;         // global row base (0..16383)
  int lrow0, N; const float* xin; const float* W; u16* yst;
  if (grow0 < 4096)       { lrow0 = grow0;         N = 4096; W = W0c; yst = yst0; xin = x0; }
  else if (grow0 < 12288) { lrow0 = grow0 - 4096;  N = 8192; W = W1c; yst = yst1; xin = x1; }
  else                    { lrow0 = grow0 - 12288; N = 4096; W = W2c; yst = yst2; xin = x2; }
  const float* xsrc = layer ? (xbuf + (size_t)grow0 * 64) : (xin + (size_t)lrow0 * 64);
  W += layer * 4096;

  __shared__ u16 xt[64 * 72];   // xt[j][k], stride 72 pad
  __shared__ u16 wt[64 * 72];   // wt[c][k] = W[k][c] (transposed)

  int tid = threadIdx.x;
  {
    int j  = tid >> 2;
    int c0 = (tid & 3) * 16;
    const float* src = xsrc + j * 64 + c0;
    #pragma unroll
    for (int i = 0; i < 4; i++){
      float4 v = *(const float4*)(src + i * 4);
      int o = j * 72 + c0 + i * 4;
      xt[o + 0] = f2bf(v.x); xt[o + 1] = f2bf(v.y);
      xt[o + 2] = f2bf(v.z); xt[o + 3] = f2bf(v.w);
    }
    const float* wsrc = W + j * 64 + c0;   // j doubles as k-index for W staging
    #pragma unroll
    for (int i = 0; i < 4; i++){
      float4 v = *(const float4*)(wsrc + i * 4);
      int c = c0 + i * 4;
      wt[(c + 0) * 72 + j] = f2bf(v.x);
      wt[(c + 1) * 72 + j] = f2bf(v.y);
      wt[(c + 2) * 72 + j] = f2bf(v.z);
      wt[(c + 3) * 72 + j] = f2bf(v.w);
    }
  }
  __syncthreads();

  int lane = tid & 63, w = tid >> 6;
  int m = lane & 15, q = lane >> 4;
  floatx4 acc[4] = {};
  #pragma unroll
  for (int kk = 0; kk < 2; kk++){
    short8 af = *(const short8*)(&xt[(w * 16 + m) * 72 + kk * 32 + q * 8]);
    #pragma unroll
    for (int ct = 0; ct < 4; ct++){
      short8 bf = *(const short8*)(&wt[(ct * 16 + m) * 72 + kk * 32 + q * 8]);
      acc[ct] = __builtin_amdgcn_mfma_f32_16x16x32_bf16(af, bf, acc[ct], 0, 0, 0);
    }
  }
  // C layout: row(j) = q*4+r (+w*16), col(c) = m (+ct*16)   [m89-verified]
  #pragma unroll
  for (int r = 0; r < 4; r++){
    int j = w * 16 + q * 4 + r;
    float di = dinv[grow0 + j];
    #pragma unroll
    for (int ct = 0; ct < 4; ct++){
      int c = ct * 16 + m;
      yst[(size_t)c * N + lrow0 + j] = f2bf(acc[ct][r] * di);
    }
  }
}

// ---------------------------------------------------------------------------
// Big GEMM on bf16 L: part[h][i][c] = sum_{k in half h} lb[i][k] * Yst[c][k]
// 512 blocks: rank0 [0,128), rank1 [128,384), rank2 [384,512).
// Block = (mblock, khalf h): 64 rows x 64 cols; 4 waves split the K-half
// 4-way, NO barriers in the K loop.
//   A path: global_load_lds DMA (16B/lane) into wave-private double-buffered
//   linear LDS tile [64][64] bf16 (8 KB x2 per wave). Rule #21 XOR swizzle:
//   source chunk = (lane&7)^(lane>>3); read chunk = (kk*4+q)^(m&7). Per-octet
//   bank-conflict-free ds_read_b128.
//   B path (yst, L2-resident): global->reg, register double-buffered.
//   Counted s_waitcnt vmcnt(16): each wave always keeps the next tile's
//   16 x 1KB loads in flight; never drains to 0 inside the loop (T4).
// ---------------------------------------------------------------------------
struct BS { short8 b[8]; };     // [kk*4+ct]

__device__ __forceinline__ void loadB8(BS& s, const u16* __restrict__ yst,
                                       const int boff[4], int k){
  #pragma unroll
  for (int ct = 0; ct < 4; ct++){
    s.b[ct]     = *(const short8*)(yst + boff[ct] + k);
    s.b[4 + ct] = *(const short8*)(yst + boff[ct] + k + 32);
  }
}

// apl: per-lane global src (row = m0+8rr+(lane>>3), chunk = (lane&7)^(lane>>3))
// buf: wave-uniform LDS tile base (linear [64 rows][64 k] bf16)
__device__ __forceinline__ void stageA(const u16* apl, u16* buf, int N){
  #pragma unroll
  for (int rr = 0; rr < 8; rr++)
    __builtin_amdgcn_global_load_lds(
        (const __attribute__((address_space(1))) void*)(apl + (size_t)rr * 8 * N),
        (__attribute__((address_space(3))) void*)(buf + rr * 512),
        16, 0, 0);
}

__device__ __forceinline__ void computeTile(const u16* buf, const BS& B,
                                            floatx4 acc[4][4], int m, int q){
  #pragma unroll
  for (int kk = 0; kk < 2; kk++){
    short8 a[4];
    #pragma unroll
    for (int rt = 0; rt < 4; rt++)
      a[rt] = *(const short8*)(buf + (rt * 16 + m) * 64
                               + (((kk * 4 + q) ^ (m & 7)) * 8));
    #pragma unroll
    for (int rt = 0; rt < 4; rt++)
      #pragma unroll
      for (int ct = 0; ct < 4; ct++)
        acc[rt][ct] = __builtin_amdgcn_mfma_f32_16x16x32_bf16(
                        a[rt], B.b[kk * 4 + ct], acc[rt][ct], 0, 0, 0);
  }
}

__global__ __launch_bounds__(256, 2) void gemm_kernel(
    const u16* __restrict__ lb,
    const u16* __restrict__ yst0, const u16* __restrict__ yst1,
    const u16* __restrict__ yst2, float* __restrict__ part)
{
  int b = blockIdx.x;
  const u16* A; const u16* yst; int N, growoff, mb, h;
  if (b < 128)      { A = lb;             yst = yst0; N = 4096; growoff = 0;     mb = b >> 1;         h = b & 1; }
  else if (b < 384) { A = lb + 16777216u; yst = yst1; N = 8192; growoff = 4096;  mb = (b - 128) >> 1; h = b & 1; }
  else              { A = lb + 83886080u; yst = yst2; N = 4096; growoff = 12288; mb = (b - 384) >> 1; h = b & 1; }
  int m0 = mb * 64;
  int tid = threadIdx.x, lane = tid & 63, w = tid >> 6;
  int m = lane & 15, q = lane >> 4;
  int kstart = h * (N >> 1) + w * (N >> 3);
  int T = N >> 9;                     // 64-k tiles per wave (8 or 16), even

  // 64 KB shared: during K-loop = 4 wave-private double-buffered A tiles
  // (4 x 2 x 8 KB, linear); after a barrier, reused as the 4x(64x64) fp32
  // reduction buffer.
  __shared__ char shraw[65536];
  u16* myt  = (u16*)shraw + w * 8192;      // 2 bufs x 4096 u16
  u16* buf0 = myt;
  u16* buf1 = myt + 4096;

  int boff[4];
  #pragma unroll
  for (int ct = 0; ct < 4; ct++) boff[ct] = (ct * 16 + m) * N + q * 8;
  const u16* apl = A + (size_t)(m0 + (lane >> 3)) * N + kstart
                 + (((lane & 7) ^ (lane >> 3)) * 8);

  floatx4 acc[4][4] = {};
  BS bA, bB;
  loadB8(bA, yst, boff, kstart);           // B(0)
  stageA(apl, buf0, N);                    // A(0) -> buf0
  int kb = kstart;
  for (int t = 0; t < T; t += 2){
    // prefetch tile t+1, compute tile t
    loadB8(bB, yst, boff, kb + 64);
    stageA(apl + 64, buf1, N);
    asm volatile("s_waitcnt vmcnt(16)" ::: "memory");   // drain B(t)+A(t)
    computeTile(buf0, bA, acc, m, q);
    // prefetch tile t+2, compute tile t+1
    if (t + 2 < T){
      loadB8(bA, yst, boff, kb + 128);
      stageA(apl + 128, buf0, N);
      asm volatile("s_waitcnt vmcnt(16)" ::: "memory"); // drain B(t+1)+A(t+1)
    } else {
      asm volatile("s_waitcnt vmcnt(0)" ::: "memory");
    }
    computeTile(buf1, bB, acc, m, q);
    apl += 128; kb += 128;
  }

  // cross-wave reduction: reuse shraw as red[4][64*64] fp32
  __syncthreads();                                   // all frag reads done
  float* red = (float*)shraw;
  #pragma unroll
  for (int rt = 0; rt < 4; rt++)
    #pragma unroll
    for (int ct = 0; ct < 4; ct++)
      #pragma unroll
      for (int r = 0; r < 4; r++){
        int row = rt * 16 + q * 4 + r;
        int col = ct * 16 + m;
        red[w * 4096 + row * 64 + col] = acc[rt][ct][r];
      }
  __syncthreads();
  float4* dst = (float4*)(part + (size_t)h * 16384 * 64 + (size_t)(growoff + m0) * 64);
  const float4* r0 = (const float4*)(red);
  const float4* r1 = (const float4*)(red + 4096);
  const float4* r2 = (const float4*)(red + 8192);
  const float4* r3 = (const float4*)(red + 12288);
  #pragma unroll
  for (int i = 0; i < 4; i++){
    int e = tid + i * 256;
    float4 v0 = r0[e], v1 = r1[e], v2 = r2[e], v3 = r3[e];
    float4 o;
    o.x = v0.x + v1.x + v2.x + v3.x;
    o.y = v0.y + v1.y + v2.y + v3.y;
    o.z = v0.z + v1.z + v2.z + v3.z;
    o.w = v0.w + v1.w + v2.w + v3.w;
    dst[e] = o;
  }
}

// ---------------------------------------------------------------------------
// epilogue: x[i][c] = relu(dinv[i] * (part0[i][c] + part1[i][c]))
// ---------------------------------------------------------------------------
__global__ __launch_bounds__(256) void epi_kernel(
    const float* __restrict__ part, const float* __restrict__ dinv,
    float* __restrict__ xbuf)
{
  int e4 = blockIdx.x * 256 + threadIdx.x;      // 262144 float4 groups
  const float4* p0 = (const float4*)part;
  const float4* p1 = (const float4*)(part + 16384 * 64);
  float4 v0 = p0[e4], v1 = p1[e4];
  float di = dinv[e4 >> 4];
  float4 o;
  o.x = fmaxf(di * (v0.x + v1.x), 0.f);
  o.y = fmaxf(di * (v0.y + v1.y), 0.f);
  o.z = fmaxf(di * (v0.z + v1.z), 0.f);
  o.w = fmaxf(di * (v0.w + v1.w), 0.f);
  ((float4*)xbuf)[e4] = o;
}

// ---------------------------------------------------------------------------
// pooling: pooled[r][seg][c] = sum_{i: bel_r[i]==seg} x[i][c]
// ---------------------------------------------------------------------------
__global__ __launch_bounds__(256) void pool_kernel(
    const float* __restrict__ xbuf,
    const int* __restrict__ bel0, const int* __restrict__ bel1,
    const int* __restrict__ bel2, float* __restrict__ pooled)
{
  int rb = blockIdx.x;                 // 0..191
  int r = rb >> 6, seg = rb & 63;
  int lane = threadIdx.x & 63, w = threadIdx.x >> 6;
  const int* bel; const float* x; int N;
  if (r == 0)      { bel = bel0; x = xbuf;               N = 4096; }
  else if (r == 1) { bel = bel1; x = xbuf + 4096 * 64;   N = 8192; }
  else             { bel = bel2; x = xbuf + 12288 * 64;  N = 4096; }
  float acc = 0.f;
  for (int i0 = w * 64; i0 < N; i0 += 256){
    int bv = bel[i0 + lane];
    unsigned long long mask = __ballot(bv == seg);
    while (mask){
      int idx = __builtin_ctzll(mask);
      mask &= mask - 1;
      acc += x[(size_t)(i0 + idx) * 64 + lane];
    }
  }
  __shared__ float red[4][64];
  red[w][lane] = acc;
  __syncthreads();
  if (w == 0)
    pooled[rb * 64 + lane] = red[0][lane] + red[1][lane] + red[2][lane] + red[3][lane];
}

// ---------------------------------------------------------------------------
// readout: out[b][o] = sum_r ( pooled[r][b] @ Wr_r + br_r )[o]
// ---------------------------------------------------------------------------
__global__ __launch_bounds__(256) void readout_kernel(
    const float* __restrict__ pooled,
    const float* __restrict__ Wr0, const float* __restrict__ br0,
    const float* __restrict__ Wr1, const float* __restrict__ br1,
    const float* __restrict__ Wr2, const float* __restrict__ br2,
    float* __restrict__ out)
{
  int t = blockIdx.x * 256 + threadIdx.x;   // 2048 outputs
  int bseg = t >> 5, o = t & 31;
  float s = br0[o] + br1[o] + br2[o];
  const float* p0 = pooled + bseg * 64;
  const float* p1 = pooled + (64 + bseg) * 64;
  const float* p2 = pooled + (128 + bseg) * 64;
  for (int c = 0; c < 64; c++){
    s += p0[c] * Wr0[c * 32 + o];
    s += p1[c] * Wr1[c * 32 + o];
    s += p2[c] * Wr2[c * 32 + o];
  }
  out[t] = s;
}

// ---------------------------------------------------------------------------
extern "C" void kernel_launch(void* const* d_in, const int* in_sizes, int n_in,
                              void* d_out, int out_size, void* d_ws, size_t ws_size,
                              hipStream_t stream)
{
  const float* x0  = (const float*)d_in[0];
  const float* x1  = (const float*)d_in[1];
  const float* x2  = (const float*)d_in[2];
  const float* L0  = (const float*)d_in[3];
  const float* L1  = (const float*)d_in[4];
  const float* L2  = (const float*)d_in[5];
  const int*   bel0 = (const int*)d_in[6];
  const int*   bel1 = (const int*)d_in[7];
  const int*   bel2 = (const int*)d_in[8];
  const float* W0  = (const float*)d_in[9];
  const float* W1  = (const float*)d_in[10];
  const float* W2  = (const float*)d_in[11];
  const float* Wr0 = (const float*)d_in[12];
  const float* br0 = (const float*)d_in[13];
  const float* Wr1 = (const float*)d_in[14];
  const float* br1 = (const float*)d_in[15];
  const float* Wr2 = (const float*)d_in[16];
  const float* br2 = (const float*)d_in[17];

  // workspace layout (~216 MB; ws is ~1 GB per harness fill size)
  float* dinv   = (float*)d_ws;                  // 16384 f32
  float* xbuf   = dinv + 16384;                  // 16384*64 f32 (4 MB)
  float* part   = xbuf + 1048576;                // 2*16384*64 f32 (8 MB)
  float* pooled = part + 2097152;                // 3*64*64 f32
  u16*   yst    = (u16*)(pooled + 12288);        // 1,048,576 bf16 (2 MB)
  u16*   lb     = yst + 1048576;                 // 100,663,296 bf16 (201 MB)
  u16* yst0 = yst;
  u16* yst1 = yst + 64 * 4096;
  u16* yst2 = yst1 + 64 * 8192;

  conv_rowsum_kernel<<<4096, 256, 0, stream>>>(L0, L1, L2, lb, dinv);
  for (int layer = 0; layer < 2; layer++){
    xw_kernel<<<256, 256, 0, stream>>>(x0, x1, x2, xbuf, W0, W1, W2, layer,
                                       dinv, yst0, yst1, yst2);
    gemm_kernel<<<512, 256, 0, stream>>>(lb, yst0, yst1, yst2, part);
    epi_kernel<<<1024, 256, 0, stream>>>(part, dinv, xbuf);
  }
  pool_kernel<<<192, 256, 0, stream>>>(xbuf, bel0, bel1, bel2, pooled);
  readout_kernel<<<8, 256, 0, stream>>>(pooled, Wr0, br0, Wr1, br1, Wr2, br2,
                                        (float*)d_out);
}